// Round 6
// baseline (3701.539 us; speedup 1.0000x reference)
//
#include <hip/hip_runtime.h>
#include <hip/hip_fp16.h>

#define B_  256
#define T_  96
#define IN_ 512
#define H_  1024
#define K1  1536          // H + IN
#define NT  (B_*T_)       // 24576

// recur_k: 4 groups x 64 blocks; group owns 64 batch rows; block owns 16 cols
// of W1/W2/W3 (rows 16j..16j+16 of each), held in REGISTERS per K-split wave.
// LDS only for cross-wave K-reduction:
#define SLOT   1280        // one 16x16 f32 frag, col stride 80 B (bank-spread)
#define RED1_OFF 0         // P1: [mi][writer w][nf] = 32 slots
#define RED2_OFF 40960     // P2: [mi][writer w]     = 16 slots
#define LDSB   61440

typedef _Float16 f16x8 __attribute__((ext_vector_type(8)));
typedef float    f32x4 __attribute__((ext_vector_type(4)));

__device__ __forceinline__ float sigmoidf_(float z) { return 1.f/(1.f+__expf(-z)); }
__device__ __forceinline__ float tanhf_(float z)    { return 1.f - 2.f/(__expf(2.f*z)+1.f); }

// coherent (cross-XCD) access: bypass L1 + per-XCD L2, straight to coherence pt
__device__ __forceinline__ uint4 ld_coh_b128(const void* p){
    uint4 r; asm volatile("global_load_dwordx4 %0, %1, off sc0 sc1" : "=&v"(r) : "v"(p)); return r;
}
__device__ __forceinline__ uint4 ld_b128(const void* p){
    uint4 r; asm volatile("global_load_dwordx4 %0, %1, off" : "=&v"(r) : "v"(p)); return r;
}
__device__ __forceinline__ void st_coh_u16(void* p, unsigned v){
    asm volatile("global_store_short %0, %1, off sc0 sc1" :: "v"(p), "v"(v) : "memory");
}
#define WAITV0 do { asm volatile("s_waitcnt vmcnt(0)" ::: "memory"); \
                    __builtin_amdgcn_sched_barrier(0); } while(0)
__device__ __forceinline__ void waitv0_(){ asm volatile("s_waitcnt vmcnt(0)" ::: "memory"); }

// ---------------- prep: fp32 -> fp16 ----------------
__global__ void cvt_f32_f16_k(const float* __restrict__ src, _Float16* __restrict__ dst, int n8) {
    int i = blockIdx.x*blockDim.x + threadIdx.x;
    if (i >= n8) return;
    const float4* s = (const float4*)src;
    float4 a = s[2*(size_t)i], b = s[2*(size_t)i+1];
    f16x8 o;
    o[0]=(_Float16)a.x; o[1]=(_Float16)a.y; o[2]=(_Float16)a.z; o[3]=(_Float16)a.w;
    o[4]=(_Float16)b.x; o[5]=(_Float16)b.y; o[6]=(_Float16)b.z; o[7]=(_Float16)b.w;
    *(f16x8*)(dst + 8*(size_t)i) = o;
}

// ---------------- belta = exp(-relu(td @ Wb^T + bb)) ----------------
__global__ void __launch_bounds__(256) belta_gemm_k(const _Float16* __restrict__ td,
                                                    const _Float16* __restrict__ Wbh,
                                                    const float* __restrict__ bb,
                                                    _Float16* __restrict__ belta) {
    __shared__ _Float16 As[64][136];
    __shared__ _Float16 Bs[128][136];
    const int bid = blockIdx.x;
    const int mt = bid >> 3, nt = bid & 7;
    const int bt0 = mt*64, h0 = nt*128;
    const int tid = threadIdx.x;
    const int w = tid >> 6, l = tid & 63;
    const int wm = (w>>1)*32, wn = (w&1)*64;
    f32x4 acc[2][4] = {};
    for (int kc = 0; kc < 4; ++kc) {
        const int kbase = kc*128;
        #pragma unroll
        for (int p = 0; p < 4; ++p) {
            int unit = tid + 256*p; int r = unit>>4, cu = unit&15;
            *(uint4*)&As[r][cu*8] = *(const uint4*)(td + (size_t)(bt0+r)*IN_ + kbase + cu*8);
        }
        #pragma unroll
        for (int p = 0; p < 8; ++p) {
            int unit = tid + 256*p; int r = unit>>4, cu = unit&15;
            *(uint4*)&Bs[r][cu*8] = *(const uint4*)(Wbh + (size_t)(h0+r)*IN_ + kbase + cu*8);
        }
        __syncthreads();
        #pragma unroll
        for (int ks = 0; ks < 4; ++ks) {
            const int kk = ks*32 + (l>>4)*8;
            f16x8 a0 = *(const f16x8*)&As[wm +      (l&15)][kk];
            f16x8 a1 = *(const f16x8*)&As[wm + 16 + (l&15)][kk];
            #pragma unroll
            for (int ni = 0; ni < 4; ++ni) {
                f16x8 b = *(const f16x8*)&Bs[wn + ni*16 + (l&15)][kk];
                acc[0][ni] = __builtin_amdgcn_mfma_f32_16x16x32_f16(a0, b, acc[0][ni], 0,0,0);
                acc[1][ni] = __builtin_amdgcn_mfma_f32_16x16x32_f16(a1, b, acc[1][ni], 0,0,0);
            }
        }
        __syncthreads();
    }
    #pragma unroll
    for (int mi = 0; mi < 2; ++mi)
    #pragma unroll
    for (int ni = 0; ni < 4; ++ni)
    #pragma unroll
    for (int r = 0; r < 4; ++r) {
        int m_l = wm + mi*16 + (l>>4)*4 + r;
        int n_l = wn + ni*16 + (l&15);
        int bt = bt0 + m_l, h = h0 + n_l;
        float z = acc[mi][ni][r] + bb[h];
        belta[(size_t)bt*H_ + h] = (_Float16)__expf(-fmaxf(z, 0.f));
    }
}

// ---------------- group barrier (64 blocks, relaxed agent atomics) ----------------
__device__ __forceinline__ void group_barrier(int* flags, int gbase, int j, int it) {
    waitv0_();                 // drain inline-asm stores before publishing
    __syncthreads();
    if (threadIdx.x == 0)
        __hip_atomic_store(&flags[gbase + j], it, __ATOMIC_RELAXED, __HIP_MEMORY_SCOPE_AGENT);
    for (;;) {
        int v = __hip_atomic_load(&flags[gbase + (threadIdx.x & 63)],
                                  __ATOMIC_RELAXED, __HIP_MEMORY_SCOPE_AGENT);
        if (__syncthreads_count(v < it) == 0) break;
        __builtin_amdgcn_s_sleep(2);
    }
}

// ---------------- recurrent scan: register weights, K-split waves ----------------
__global__ void __launch_bounds__(256, 1) recur_k(
    const _Float16* __restrict__ xh,     // (B,T,IN) fp16, plain cached
    const _Float16* __restrict__ belh,   // (B,T,H) fp16, plain cached
    const float* __restrict__ W1, const float* __restrict__ W2, const float* __restrict__ W3,
    const float* __restrict__ b1, const float* __restrict__ b2, const float* __restrict__ b3,
    const float* __restrict__ Wo,
    _Float16* __restrict__ ssh,          // (256,1024) scaled state — coherent exchange
    _Float16* __restrict__ rsh,          // (256,1024) r*state — coherent exchange
    int* flags, float* __restrict__ outacc)
{
    __shared__ __align__(16) char smem[LDSB];
    const int bid = blockIdx.x, tid = threadIdx.x;
    const int g = bid >> 6, j = bid & 63;
    const int gbase = g*64, grow0 = g*64;
    const int w = tid >> 6;              // wave = K-quarter index: k in [w*384, w*384+384)
    const int l = tid & 63;
    const int lh = l >> 4;               // k-subslot (8 f16) / C-row group
    const int ll = l & 15;               // B-row (weight col) / A-row / C-col
    const int kw = w*384;

    // ---- prologue: per-wave weight K-slices -> REGISTERS (fp32 -> f16) ----
    f16x8 w12f[12][2];                   // [kf][0]=W1 slice, [1]=W2 slice
    f16x8 w3f[12];
    {
        const size_t wrow = (size_t)(16*j + ll)*K1;
        #pragma unroll
        for (int kf = 0; kf < 12; ++kf) {
            int k = kw + kf*32 + lh*8;
            const float* p1 = W1 + wrow + k;
            const float* p2 = W2 + wrow + k;
            const float* p3 = W3 + wrow + k;
            float4 a0 = *(const float4*)p1, a1 = *(const float4*)(p1+4);
            float4 c0 = *(const float4*)p2, c1 = *(const float4*)(p2+4);
            float4 d0 = *(const float4*)p3, d1 = *(const float4*)(p3+4);
            f16x8 h1, h2, h3;
            h1[0]=(_Float16)a0.x; h1[1]=(_Float16)a0.y; h1[2]=(_Float16)a0.z; h1[3]=(_Float16)a0.w;
            h1[4]=(_Float16)a1.x; h1[5]=(_Float16)a1.y; h1[6]=(_Float16)a1.z; h1[7]=(_Float16)a1.w;
            h2[0]=(_Float16)c0.x; h2[1]=(_Float16)c0.y; h2[2]=(_Float16)c0.z; h2[3]=(_Float16)c0.w;
            h2[4]=(_Float16)c1.x; h2[5]=(_Float16)c1.y; h2[6]=(_Float16)c1.z; h2[7]=(_Float16)c1.w;
            h3[0]=(_Float16)d0.x; h3[1]=(_Float16)d0.y; h3[2]=(_Float16)d0.z; h3[3]=(_Float16)d0.w;
            h3[4]=(_Float16)d1.x; h3[5]=(_Float16)d1.y; h3[6]=(_Float16)d1.z; h3[7]=(_Float16)d1.w;
            w12f[kf][0]=h1; w12f[kf][1]=h2; w3f[kf]=h3;
        }
    }

    const int colU = (j<<4) + ll;                    // owned output column
    const float b1c = b1[colU], b2c = b2[colU], b3c = b3[colU];
    const float woc = Wo[colU];
    const int crow0 = grow0 + w*16 + lh*4;           // epilogue rows (+r)
    const int redb = ll*80 + lh*16;                  // in-slot byte offset

    float S_reg[4] = {0.f,0.f,0.f,0.f};
    float pout[4]  = {0.f,0.f,0.f,0.f};
    uint4 a[12][4];                                  // A frags: [kf][mi]
    int it = 0;

    for (int t = 0; t < T_; ++t) {
        float u_reg[4];
        { // ======== P1: [u|r] = sigmoid([state|x_t] @ W12^T + b) ========
            #pragma unroll
            for (int kf = 0; kf < 12; ++kf) {
                const int kb = kw + kf*32;
                const int k = kb + lh*8;
                #pragma unroll
                for (int mi = 0; mi < 4; ++mi) {
                    const int row = grow0 + mi*16 + ll;
                    if (kb < H_)
                        a[kf][mi] = ld_coh_b128(ssh + ((size_t)row<<10) + k);
                    else
                        a[kf][mi] = ld_b128(xh + ((size_t)row*T_ + t)*IN_ + (k - H_));
                }
            }
            WAITV0;
            f32x4 acc1[4][2] = {};
            #pragma unroll
            for (int kf = 0; kf < 12; ++kf)
            #pragma unroll
            for (int mi = 0; mi < 4; ++mi) {
                f16x8 av = *(const f16x8*)&a[kf][mi];
                acc1[mi][0] = __builtin_amdgcn_mfma_f32_16x16x32_f16(av, w12f[kf][0], acc1[mi][0], 0,0,0);
                acc1[mi][1] = __builtin_amdgcn_mfma_f32_16x16x32_f16(av, w12f[kf][1], acc1[mi][1], 0,0,0);
            }
            // cross-wave K-reduce: write partials for mi != w
            #pragma unroll
            for (int mi = 0; mi < 4; ++mi)
            #pragma unroll
            for (int nf = 0; nf < 2; ++nf)
                if (mi != w)
                    *(f32x4*)(smem + RED1_OFF + ((mi*4+w)*2+nf)*SLOT + redb) = acc1[mi][nf];
            f32x4 own0 = acc1[0][0], own1 = acc1[0][1];
            if (w == 1) { own0 = acc1[1][0]; own1 = acc1[1][1]; }
            if (w == 2) { own0 = acc1[2][0]; own1 = acc1[2][1]; }
            if (w == 3) { own0 = acc1[3][0]; own1 = acc1[3][1]; }
            __syncthreads();
            #pragma unroll
            for (int ws = 0; ws < 4; ++ws)
                if (ws != w) {
                    own0 += *(const f32x4*)(smem + RED1_OFF + ((w*4+ws)*2+0)*SLOT + redb);
                    own1 += *(const f32x4*)(smem + RED1_OFF + ((w*4+ws)*2+1)*SLOT + redb);
                }
            // epilogue: u kept in regs; rs = sigmoid(r)*S -> rsh (coherent)
            #pragma unroll
            for (int r = 0; r < 4; ++r) {
                u_reg[r] = sigmoidf_(own0[r] + b1c);
                float rr = sigmoidf_(own1[r] + b2c);
                _Float16 hv = (_Float16)(rr * S_reg[r]);
                st_coh_u16(rsh + ((size_t)(crow0 + r) << 10) + colU,
                           (unsigned)*(unsigned short*)&hv);
            }
        }
        group_barrier(flags, gbase, j, ++it);
        { // ======== P2: ns = tanh([r*s|x_t] @ W3^T + b3); state update ========
            // reload only the state-region frags (x frags in a[] still valid)
            #pragma unroll
            for (int kf = 0; kf < 12; ++kf) {
                const int kb = kw + kf*32;
                if (kb < H_) {
                    const int k = kb + lh*8;
                    #pragma unroll
                    for (int mi = 0; mi < 4; ++mi) {
                        const int row = grow0 + mi*16 + ll;
                        a[kf][mi] = ld_coh_b128(rsh + ((size_t)row<<10) + k);
                    }
                }
            }
            WAITV0;
            f32x4 acc2[4] = {};
            #pragma unroll
            for (int kf = 0; kf < 12; ++kf)
            #pragma unroll
            for (int mi = 0; mi < 4; ++mi) {
                f16x8 av = *(const f16x8*)&a[kf][mi];
                acc2[mi] = __builtin_amdgcn_mfma_f32_16x16x32_f16(av, w3f[kf], acc2[mi], 0,0,0);
            }
            #pragma unroll
            for (int mi = 0; mi < 4; ++mi)
                if (mi != w)
                    *(f32x4*)(smem + RED2_OFF + (mi*4+w)*SLOT + redb) = acc2[mi];
            f32x4 own2 = acc2[0];
            if (w == 1) own2 = acc2[1];
            if (w == 2) own2 = acc2[2];
            if (w == 3) own2 = acc2[3];
            __syncthreads();
            #pragma unroll
            for (int ws = 0; ws < 4; ++ws)
                if (ws != w)
                    own2 += *(const f32x4*)(smem + RED2_OFF + (w*4+ws)*SLOT + redb);
            // epilogue: snew = (1-u)*S + u*tanh(.); rescale belta(t+1); write ssh
            #pragma unroll
            for (int r = 0; r < 4; ++r) {
                float ns = tanhf_(own2[r] + b3c);
                float sn = (1.f - u_reg[r])*S_reg[r] + u_reg[r]*ns;
                if (t < T_-1) {
                    float bel = (float)belh[((size_t)(crow0 + r)*T_ + (t+1))*H_ + colU];
                    float ss = bel * sn;
                    S_reg[r] = ss;
                    _Float16 hs = (_Float16)ss;
                    st_coh_u16(ssh + ((size_t)(crow0 + r) << 10) + colU,
                               (unsigned)*(unsigned short*)&hs);
                } else {
                    pout[r] = sn * woc;
                }
            }
        }
        group_barrier(flags, gbase, j, ++it);
    }
    // ---- final: sum pout over the block's 16 cols (ll), atomicAdd per row ----
    #pragma unroll
    for (int r = 0; r < 4; ++r) {
        float v = pout[r];
        v += __shfl_xor(v, 1, 64);
        v += __shfl_xor(v, 2, 64);
        v += __shfl_xor(v, 4, 64);
        v += __shfl_xor(v, 8, 64);
        if (ll == 0) atomicAdd(&outacc[crow0 + r], v);
    }
}

__global__ void finish_k(const float* __restrict__ acc, const float* __restrict__ bo,
                         float* __restrict__ out) {
    int i = threadIdx.x;
    out[i] = sigmoidf_(acc[i] + bo[0]);
}

extern "C" void kernel_launch(void* const* d_in, const int* in_sizes, int n_in,
                              void* d_out, int out_size, void* d_ws, size_t ws_size,
                              hipStream_t stream) {
    const float* x   = (const float*)d_in[0];
    const float* td  = (const float*)d_in[1];
    const float* Wb  = (const float*)d_in[2];
    const float* bb  = (const float*)d_in[3];
    const float* W1  = (const float*)d_in[4];
    const float* b1  = (const float*)d_in[5];
    const float* W2  = (const float*)d_in[6];
    const float* b2  = (const float*)d_in[7];
    const float* W3  = (const float*)d_in[8];
    const float* b3  = (const float*)d_in[9];
    const float* Wo  = (const float*)d_in[10];
    const float* bo  = (const float*)d_in[11];
    float* out = (float*)d_out;

    char* p = (char*)d_ws;
    auto carve = [&](size_t bytes) { char* r = p; p += (bytes + 255) & ~(size_t)255; return r; };
    int*      bar    = (int*)      carve(1024);            // 256 flags
    float*    outacc = (float*)    carve(1024);            // 256 partial sums
    _Float16* ssh    = (_Float16*) carve((size_t)B_*H_*2); // scaled state exchange
    _Float16* rsh    = (_Float16*) carve((size_t)B_*H_*2); // r*state exchange
    _Float16* xh     = (_Float16*) carve((size_t)NT*IN_*2);
    _Float16* tdh    = (_Float16*) carve((size_t)NT*IN_*2);
    _Float16* belh   = (_Float16*) carve((size_t)NT*H_*2);
    _Float16* Wbh    = (_Float16*) carve((size_t)H_*IN_*2);

    // zero: flags + outacc + ssh (contiguous at front of d_ws)
    size_t zbytes = 1024 + 1024 + (size_t)B_*H_*2;
    (void)hipMemsetAsync(bar, 0, zbytes, stream);

    const int thr = 256;
    int n8;
    n8 = NT*IN_/8;    cvt_f32_f16_k<<<(n8+thr-1)/thr, thr, 0, stream>>>(x,  xh,  n8);
    n8 = NT*IN_/8;    cvt_f32_f16_k<<<(n8+thr-1)/thr, thr, 0, stream>>>(td, tdh, n8);
    n8 = H_*IN_/8;    cvt_f32_f16_k<<<(n8+thr-1)/thr, thr, 0, stream>>>(Wb, Wbh, n8);

    belta_gemm_k<<<(NT/64)*(H_/128), 256, 0, stream>>>(tdh, Wbh, bb, belh);

    recur_k<<<256, 256, 0, stream>>>(xh, belh, W1, W2, W3, b1, b2, b3, Wo,
                                     ssh, rsh, bar, outacc);
    finish_k<<<1, 256, 0, stream>>>(outacc, bo, out);
}

// Round 8
// 3193.846 us; speedup vs baseline: 1.1590x; 1.1590x over previous
//
#include <hip/hip_runtime.h>
#include <hip/hip_fp16.h>

#define B_  256
#define T_  96
#define IN_ 512
#define H_  1024
#define K1  1536          // H + IN
#define NT  (B_*T_)       // 24576

// recur_k: 4 groups x 64 blocks; group owns 64 batch rows; block owns 16 cols
// of W1/W2/W3 (rows 16j..16j+16 of each). Persistent LDS weights only:
#define W12_OFF 0          // 32 rows x 3072 B  (W1 slice rows 0-15, W2 rows 16-31)
#define W3_OFF  98304      // 16 rows x 3072 B
#define WROW    3072       // 147456 B total (<= ~163584 usable)

typedef _Float16 f16x8 __attribute__((ext_vector_type(8)));
typedef float    f32x4 __attribute__((ext_vector_type(4)));

__device__ __forceinline__ float sigmoidf_(float z) { return 1.f/(1.f+__expf(-z)); }
__device__ __forceinline__ float tanhf_(float z)    { return 1.f - 2.f/(__expf(2.f*z)+1.f); }

// Exchange protocol: STORES write through to the coherence point (sc0 sc1) so
// no dirty line ever sits in a non-coherent per-XCD L2. READS are plain cached;
// after each group barrier an agent-scope acquire fence (buffer_inv) drops the
// stale clean lines, so each XCD's L2 refills each broadcast line ONCE from L3
// and its CUs hit locally (vs 64 per-CU requests at the coherence point).
__device__ __forceinline__ uint4 ld_b128(const void* p){
    uint4 r; asm volatile("global_load_dwordx4 %0, %1, off" : "=&v"(r) : "v"(p)); return r;
}
__device__ __forceinline__ void st_coh_u16(void* p, unsigned v){
    asm volatile("global_store_short %0, %1, off sc0 sc1" :: "v"(p), "v"(v) : "memory");
}
#define WAITV(n) do { asm volatile("s_waitcnt vmcnt(" #n ")" ::: "memory"); \
                      __builtin_amdgcn_sched_barrier(0); } while(0)
__device__ __forceinline__ void waitv0_(){ asm volatile("s_waitcnt vmcnt(0)" ::: "memory"); }

// ---------------- prep: fp32 -> fp16 ----------------
__global__ void cvt_f32_f16_k(const float* __restrict__ src, _Float16* __restrict__ dst, int n8) {
    int i = blockIdx.x*blockDim.x + threadIdx.x;
    if (i >= n8) return;
    const float4* s = (const float4*)src;
    float4 a = s[2*(size_t)i], b = s[2*(size_t)i+1];
    f16x8 o;
    o[0]=(_Float16)a.x; o[1]=(_Float16)a.y; o[2]=(_Float16)a.z; o[3]=(_Float16)a.w;
    o[4]=(_Float16)b.x; o[5]=(_Float16)b.y; o[6]=(_Float16)b.z; o[7]=(_Float16)b.w;
    *(f16x8*)(dst + 8*(size_t)i) = o;
}

// ---------------- belta = exp(-relu(td @ Wb^T + bb)) ----------------
__global__ void __launch_bounds__(256) belta_gemm_k(const _Float16* __restrict__ td,
                                                    const _Float16* __restrict__ Wbh,
                                                    const float* __restrict__ bb,
                                                    _Float16* __restrict__ belta) {
    __shared__ _Float16 As[64][136];
    __shared__ _Float16 Bs[128][136];
    const int bid = blockIdx.x;
    const int mt = bid >> 3, nt = bid & 7;
    const int bt0 = mt*64, h0 = nt*128;
    const int tid = threadIdx.x;
    const int w = tid >> 6, l = tid & 63;
    const int wm = (w>>1)*32, wn = (w&1)*64;
    f32x4 acc[2][4] = {};
    for (int kc = 0; kc < 4; ++kc) {
        const int kbase = kc*128;
        #pragma unroll
        for (int p = 0; p < 4; ++p) {
            int unit = tid + 256*p; int r = unit>>4, cu = unit&15;
            *(uint4*)&As[r][cu*8] = *(const uint4*)(td + (size_t)(bt0+r)*IN_ + kbase + cu*8);
        }
        #pragma unroll
        for (int p = 0; p < 8; ++p) {
            int unit = tid + 256*p; int r = unit>>4, cu = unit&15;
            *(uint4*)&Bs[r][cu*8] = *(const uint4*)(Wbh + (size_t)(h0+r)*IN_ + kbase + cu*8);
        }
        __syncthreads();
        #pragma unroll
        for (int ks = 0; ks < 4; ++ks) {
            const int kk = ks*32 + (l>>4)*8;
            f16x8 a0 = *(const f16x8*)&As[wm +      (l&15)][kk];
            f16x8 a1 = *(const f16x8*)&As[wm + 16 + (l&15)][kk];
            #pragma unroll
            for (int ni = 0; ni < 4; ++ni) {
                f16x8 b = *(const f16x8*)&Bs[wn + ni*16 + (l&15)][kk];
                acc[0][ni] = __builtin_amdgcn_mfma_f32_16x16x32_f16(a0, b, acc[0][ni], 0,0,0);
                acc[1][ni] = __builtin_amdgcn_mfma_f32_16x16x32_f16(a1, b, acc[1][ni], 0,0,0);
            }
        }
        __syncthreads();
    }
    #pragma unroll
    for (int mi = 0; mi < 2; ++mi)
    #pragma unroll
    for (int ni = 0; ni < 4; ++ni)
    #pragma unroll
    for (int r = 0; r < 4; ++r) {
        int m_l = wm + mi*16 + (l>>4)*4 + r;
        int n_l = wn + ni*16 + (l&15);
        int bt = bt0 + m_l, h = h0 + n_l;
        float z = acc[mi][ni][r] + bb[h];
        belta[(size_t)bt*H_ + h] = (_Float16)__expf(-fmaxf(z, 0.f));
    }
}

// ---------------- group barrier (64 blocks) + L2 invalidate on exit ----------------
__device__ __forceinline__ void group_barrier(int* flags, int gbase, int j, int it) {
    waitv0_();                 // drain inline-asm stores before publishing
    __syncthreads();
    if (threadIdx.x == 0)
        __hip_atomic_store(&flags[gbase + j], it, __ATOMIC_RELAXED, __HIP_MEMORY_SCOPE_AGENT);
    for (;;) {
        int v = __hip_atomic_load(&flags[gbase + (threadIdx.x & 63)],
                                  __ATOMIC_RELAXED, __HIP_MEMORY_SCOPE_AGENT);
        if (__syncthreads_count(v < it) == 0) break;
        __builtin_amdgcn_s_sleep(4);
    }
    // acquire: invalidate stale clean L2/L1 lines so cached exchange reads
    // refill from the coherence point (once per XCD, then L2-hit).
    __builtin_amdgcn_fence(__ATOMIC_ACQUIRE, "agent");
    __builtin_amdgcn_sched_barrier(0);
}

// ---------------- recurrent scan: LDS weights + fragment-direct A ----------------
__global__ void __launch_bounds__(256, 1) recur_k(
    const _Float16* __restrict__ xh,     // (B,T,IN) fp16, plain cached
    const _Float16* __restrict__ belh,   // (B,T,H) fp16, plain cached
    const float* __restrict__ W1, const float* __restrict__ W2, const float* __restrict__ W3,
    const float* __restrict__ b1, const float* __restrict__ b2, const float* __restrict__ b3,
    const float* __restrict__ Wo,
    _Float16* __restrict__ ssh,          // (256,1024) scaled state exchange
    _Float16* __restrict__ rsh,          // (256,1024) r*state exchange
    int* flags, float* __restrict__ outacc)
{
    __shared__ __align__(16) char smem[147456];
    const int bid = blockIdx.x, tid = threadIdx.x;
    const int g = bid >> 6, j = bid & 63;
    const int gbase = g*64, grow0 = g*64;
    const int w = tid >> 6;              // wave = M-fragment index (rows w*16..w*16+15)
    const int l = tid & 63;
    const int lh = l >> 4;               // k-slot
    const int ll = l & 15;               // col / A-row / B-row within fragment

    // ---- prologue: persistent weight slices -> LDS (f32->f16, XOR-swizzled) ----
    for (int u = tid; u < 32*192; u += 256) {        // W12: 32 rows x 192 16B-slots
        int row = u / 192, slot = u - row*192;
        const float* src = (row < 16) ? (W1 + ((size_t)(16*j + row))*K1 + slot*8)
                                      : (W2 + ((size_t)(16*j + row-16))*K1 + slot*8);
        float4 f0 = *(const float4*)src, f1 = *(const float4*)(src+4);
        f16x8 h;
        h[0]=(_Float16)f0.x; h[1]=(_Float16)f0.y; h[2]=(_Float16)f0.z; h[3]=(_Float16)f0.w;
        h[4]=(_Float16)f1.x; h[5]=(_Float16)f1.y; h[6]=(_Float16)f1.z; h[7]=(_Float16)f1.w;
        *(f16x8*)(smem + W12_OFF + row*WROW + ((slot*16) ^ ((row&7)<<4))) = h;
    }
    for (int u = tid; u < 16*192; u += 256) {        // W3: 16 rows x 192 slots
        int row = u / 192, slot = u - row*192;
        const float* src = W3 + ((size_t)(16*j + row))*K1 + slot*8;
        float4 f0 = *(const float4*)src, f1 = *(const float4*)(src+4);
        f16x8 h;
        h[0]=(_Float16)f0.x; h[1]=(_Float16)f0.y; h[2]=(_Float16)f0.z; h[3]=(_Float16)f0.w;
        h[4]=(_Float16)f1.x; h[5]=(_Float16)f1.y; h[6]=(_Float16)f1.z; h[7]=(_Float16)f1.w;
        *(f16x8*)(smem + W3_OFF + row*WROW + ((slot*16) ^ ((row&7)<<4))) = h;
    }
    __syncthreads();

    const int colU = (j<<4) + ll;                    // owned output column
    const float b1c = b1[colU], b2c = b2[colU], b3c = b3[colU];
    const float woc = Wo[colU];

    // per-lane A-load bases: row = grow0 + w*16 + ll, k-offset lh*8
    const _Float16* srow_s = ssh + ((size_t)(grow0 + w*16 + ll) << 10) + lh*8;
    const _Float16* srow_r = rsh + ((size_t)(grow0 + w*16 + ll) << 10) + lh*8;
    const _Float16* xrow   = xh + (size_t)(grow0 + w*16 + ll) * T_ * IN_ + lh*8;
    // per-lane C/epilogue rows: grow0 + w*16 + lh*4 + r, col colU
    const int crow0 = grow0 + w*16 + lh*4;

    float S_reg[4] = {0.f,0.f,0.f,0.f};
    float pout[4]  = {0.f,0.f,0.f,0.f};
    int it = 0;

    for (int t = 0; t < T_; ++t) {
        const _Float16* xrt = xrow + (size_t)t * IN_;
        float u_reg[4];
        { // ---- P1: [u|r] = sigmoid([state|x_t] @ W12^T + b) ----
            f32x4 acc1[2] = {};
            uint4 ab[5][4];
            #define ISSUE1(S, DST) do { \
                if ((S) < 8) { _Pragma("unroll") for (int kf=0;kf<4;++kf) \
                    DST[kf] = ld_b128(srow_s + (S)*128 + kf*32); } \
                else { _Pragma("unroll") for (int kf=0;kf<4;++kf) \
                    DST[kf] = ld_b128(xrt + ((S)-8)*128 + kf*32); } } while(0)
            ISSUE1(0, ab[0]); ISSUE1(1, ab[1]); ISSUE1(2, ab[2]); ISSUE1(3, ab[3]);
            #pragma unroll
            for (int s = 0; s < 12; ++s) {
                if (s+4 < 12) ISSUE1(s+4, ab[(s+4)%5]);
                if      (s <= 7) { WAITV(16); }
                else if (s == 8) { WAITV(12); }
                else if (s == 9) { WAITV(8);  }
                else if (s ==10) { WAITV(4);  }
                else             { WAITV(0);  }
                #pragma unroll
                for (int kf = 0; kf < 4; ++kf) {
                    f16x8 a = *(const f16x8*)&ab[s%5][kf];
                    #pragma unroll
                    for (int nf = 0; nf < 2; ++nf) {
                        const int br = nf*16 + ll;
                        f16x8 b = *(const f16x8*)(smem + W12_OFF + br*WROW
                                    + ((s*256 + kf*64 + lh*16) ^ ((ll&7)<<4)));
                        acc1[nf] = __builtin_amdgcn_mfma_f32_16x16x32_f16(a, b, acc1[nf], 0,0,0);
                    }
                }
            }
            #undef ISSUE1
            #pragma unroll
            for (int r = 0; r < 4; ++r) {
                u_reg[r] = sigmoidf_(acc1[0][r] + b1c);
                float rr = sigmoidf_(acc1[1][r] + b2c);
                _Float16 hv = (_Float16)(rr * S_reg[r]);
                st_coh_u16(rsh + ((size_t)(crow0 + r) << 10) + colU,
                           (unsigned)*(unsigned short*)&hv);
            }
        }
        group_barrier(flags, gbase, j, ++it);
        { // ---- P2: ns = tanh([r*s|x_t] @ W3^T + b3); state update ----
            f32x4 acc2 = {};
            uint4 ab[5][4];
            #define ISSUE2(S, DST) do { \
                if ((S) < 8) { _Pragma("unroll") for (int kf=0;kf<4;++kf) \
                    DST[kf] = ld_b128(srow_r + (S)*128 + kf*32); } \
                else { _Pragma("unroll") for (int kf=0;kf<4;++kf) \
                    DST[kf] = ld_b128(xrt + ((S)-8)*128 + kf*32); } } while(0)
            ISSUE2(0, ab[0]); ISSUE2(1, ab[1]); ISSUE2(2, ab[2]); ISSUE2(3, ab[3]);
            #pragma unroll
            for (int s = 0; s < 12; ++s) {
                if (s+4 < 12) ISSUE2(s+4, ab[(s+4)%5]);
                if      (s <= 7) { WAITV(16); }
                else if (s == 8) { WAITV(12); }
                else if (s == 9) { WAITV(8);  }
                else if (s ==10) { WAITV(4);  }
                else             { WAITV(0);  }
                #pragma unroll
                for (int kf = 0; kf < 4; ++kf) {
                    f16x8 a = *(const f16x8*)&ab[s%5][kf];
                    f16x8 b = *(const f16x8*)(smem + W3_OFF + ll*WROW
                                + ((s*256 + kf*64 + lh*16) ^ ((ll&7)<<4)));
                    acc2 = __builtin_amdgcn_mfma_f32_16x16x32_f16(a, b, acc2, 0,0,0);
                }
            }
            #undef ISSUE2
            #pragma unroll
            for (int r = 0; r < 4; ++r) {
                float ns = tanhf_(acc2[r] + b3c);
                float sn = (1.f - u_reg[r])*S_reg[r] + u_reg[r]*ns;
                if (t < T_-1) {
                    float bel = (float)belh[((size_t)(crow0 + r)*T_ + (t+1))*H_ + colU];
                    float ss = bel * sn;
                    S_reg[r] = ss;
                    _Float16 hs = (_Float16)ss;
                    st_coh_u16(ssh + ((size_t)(crow0 + r) << 10) + colU,
                               (unsigned)*(unsigned short*)&hs);
                } else {
                    pout[r] = sn * woc;
                }
            }
        }
        group_barrier(flags, gbase, j, ++it);
    }
    // ---- final: sum pout over the block's 16 cols (ll), atomicAdd per row ----
    #pragma unroll
    for (int r = 0; r < 4; ++r) {
        float v = pout[r];
        v += __shfl_xor(v, 1, 64);
        v += __shfl_xor(v, 2, 64);
        v += __shfl_xor(v, 4, 64);
        v += __shfl_xor(v, 8, 64);
        if (ll == 0) atomicAdd(&outacc[crow0 + r], v);
    }
}

__global__ void finish_k(const float* __restrict__ acc, const float* __restrict__ bo,
                         float* __restrict__ out) {
    int i = threadIdx.x;
    out[i] = sigmoidf_(acc[i] + bo[0]);
}

extern "C" void kernel_launch(void* const* d_in, const int* in_sizes, int n_in,
                              void* d_out, int out_size, void* d_ws, size_t ws_size,
                              hipStream_t stream) {
    const float* x   = (const float*)d_in[0];
    const float* td  = (const float*)d_in[1];
    const float* Wb  = (const float*)d_in[2];
    const float* bb  = (const float*)d_in[3];
    const float* W1  = (const float*)d_in[4];
    const float* b1  = (const float*)d_in[5];
    const float* W2  = (const float*)d_in[6];
    const float* b2  = (const float*)d_in[7];
    const float* W3  = (const float*)d_in[8];
    const float* b3  = (const float*)d_in[9];
    const float* Wo  = (const float*)d_in[10];
    const float* bo  = (const float*)d_in[11];
    float* out = (float*)d_out;

    char* p = (char*)d_ws;
    auto carve = [&](size_t bytes) { char* r = p; p += (bytes + 255) & ~(size_t)255; return r; };
    int*      bar    = (int*)      carve(1024);            // 256 flags
    float*    outacc = (float*)    carve(1024);            // 256 partial sums
    _Float16* ssh    = (_Float16*) carve((size_t)B_*H_*2); // scaled state exchange
    _Float16* rsh    = (_Float16*) carve((size_t)B_*H_*2); // r*state exchange
    _Float16* xh     = (_Float16*) carve((size_t)NT*IN_*2);
    _Float16* tdh    = (_Float16*) carve((size_t)NT*IN_*2);
    _Float16* belh   = (_Float16*) carve((size_t)NT*H_*2);
    _Float16* Wbh    = (_Float16*) carve((size_t)H_*IN_*2);

    // zero: flags + outacc + ssh (contiguous at front of d_ws)
    size_t zbytes = 1024 + 1024 + (size_t)B_*H_*2;
    (void)hipMemsetAsync(bar, 0, zbytes, stream);

    const int thr = 256;
    int n8;
    n8 = NT*IN_/8;    cvt_f32_f16_k<<<(n8+thr-1)/thr, thr, 0, stream>>>(x,  xh,  n8);
    n8 = NT*IN_/8;    cvt_f32_f16_k<<<(n8+thr-1)/thr, thr, 0, stream>>>(td, tdh, n8);
    n8 = H_*IN_/8;    cvt_f32_f16_k<<<(n8+thr-1)/thr, thr, 0, stream>>>(Wb, Wbh, n8);

    belta_gemm_k<<<(NT/64)*(H_/128), 256, 0, stream>>>(tdh, Wbh, bb, belh);

    recur_k<<<256, 256, 0, stream>>>(xh, belh, W1, W2, W3, b1, b2, b3, Wo,
                                     ssh, rsh, bar, outacc);
    finish_k<<<1, 256, 0, stream>>>(outacc, bo, out);
}

// Round 10
// 2220.918 us; speedup vs baseline: 1.6667x; 1.4381x over previous
//
#include <hip/hip_runtime.h>
#include <hip/hip_fp16.h>

#define B_  256
#define T_  96
#define IN_ 512
#define H_  1024
#define K1  1536          // H + IN
#define NT  (B_*T_)       // 24576

// recur_k: 4 groups x 64 blocks; group owns 64 batch rows; block owns 16 cols
// of W1/W2/W3. Persistent LDS weights, K-MAJOR layout (conflict-free b128):
//   W12: addr = W12_OFF + (k8*32 + row)*16, k8 = k/8 in [0,192), row in [0,32)
//   W3 : addr = W3_OFF  + (k8*16 + row)*16, row in [0,16)
#define W12_OFF 0          // 98304 B
#define W3_OFF  98304      // 49152 B -> total 147456 B
typedef _Float16 f16x8 __attribute__((ext_vector_type(8)));
typedef float    f32x4 __attribute__((ext_vector_type(4)));

__device__ __forceinline__ float sigmoidf_(float z) { return 1.f/(1.f+__expf(-z)); }
__device__ __forceinline__ float tanhf_(float z)    { return 1.f - 2.f/(__expf(2.f*z)+1.f); }

// coherent (cross-XCD) access: bypass L1 + per-XCD L2
__device__ __forceinline__ uint4 ld_coh_b128(const void* p){
    uint4 r; asm volatile("global_load_dwordx4 %0, %1, off sc0 sc1" : "=&v"(r) : "v"(p)); return r;
}
__device__ __forceinline__ uint4 ld_b128(const void* p){
    uint4 r; asm volatile("global_load_dwordx4 %0, %1, off" : "=&v"(r) : "v"(p)); return r;
}
__device__ __forceinline__ unsigned ld_u16(const void* p){
    unsigned r; asm volatile("global_load_ushort %0, %1, off" : "=&v"(r) : "v"(p)); return r;
}
__device__ __forceinline__ void st_coh_u16(void* p, unsigned v){
    asm volatile("global_store_short %0, %1, off sc0 sc1" :: "v"(p), "v"(v) : "memory");
}
#define WAITV(n) do { asm volatile("s_waitcnt vmcnt(" #n ")" ::: "memory"); \
                      __builtin_amdgcn_sched_barrier(0); } while(0)
__device__ __forceinline__ void waitv0_(){ asm volatile("s_waitcnt vmcnt(0)" ::: "memory"); }

// ---------------- prep: fp32 -> fp16 ----------------
__global__ void cvt_f32_f16_k(const float* __restrict__ src, _Float16* __restrict__ dst, int n8) {
    int i = blockIdx.x*blockDim.x + threadIdx.x;
    if (i >= n8) return;
    const float4* s = (const float4*)src;
    float4 a = s[2*(size_t)i], b = s[2*(size_t)i+1];
    f16x8 o;
    o[0]=(_Float16)a.x; o[1]=(_Float16)a.y; o[2]=(_Float16)a.z; o[3]=(_Float16)a.w;
    o[4]=(_Float16)b.x; o[5]=(_Float16)b.y; o[6]=(_Float16)b.z; o[7]=(_Float16)b.w;
    *(f16x8*)(dst + 8*(size_t)i) = o;
}

// ---------------- belta = exp(-relu(td @ Wb^T + bb)) ----------------
__global__ void __launch_bounds__(256) belta_gemm_k(const _Float16* __restrict__ td,
                                                    const _Float16* __restrict__ Wbh,
                                                    const float* __restrict__ bb,
                                                    _Float16* __restrict__ belta) {
    __shared__ _Float16 As[64][136];
    __shared__ _Float16 Bs[128][136];
    const int bid = blockIdx.x;
    const int mt = bid >> 3, nt = bid & 7;
    const int bt0 = mt*64, h0 = nt*128;
    const int tid = threadIdx.x;
    const int w = tid >> 6, l = tid & 63;
    const int wm = (w>>1)*32, wn = (w&1)*64;
    f32x4 acc[2][4] = {};
    for (int kc = 0; kc < 4; ++kc) {
        const int kbase = kc*128;
        #pragma unroll
        for (int p = 0; p < 4; ++p) {
            int unit = tid + 256*p; int r = unit>>4, cu = unit&15;
            *(uint4*)&As[r][cu*8] = *(const uint4*)(td + (size_t)(bt0+r)*IN_ + kbase + cu*8);
        }
        #pragma unroll
        for (int p = 0; p < 8; ++p) {
            int unit = tid + 256*p; int r = unit>>4, cu = unit&15;
            *(uint4*)&Bs[r][cu*8] = *(const uint4*)(Wbh + (size_t)(h0+r)*IN_ + kbase + cu*8);
        }
        __syncthreads();
        #pragma unroll
        for (int ks = 0; ks < 4; ++ks) {
            const int kk = ks*32 + (l>>4)*8;
            f16x8 a0 = *(const f16x8*)&As[wm +      (l&15)][kk];
            f16x8 a1 = *(const f16x8*)&As[wm + 16 + (l&15)][kk];
            #pragma unroll
            for (int ni = 0; ni < 4; ++ni) {
                f16x8 b = *(const f16x8*)&Bs[wn + ni*16 + (l&15)][kk];
                acc[0][ni] = __builtin_amdgcn_mfma_f32_16x16x32_f16(a0, b, acc[0][ni], 0,0,0);
                acc[1][ni] = __builtin_amdgcn_mfma_f32_16x16x32_f16(a1, b, acc[1][ni], 0,0,0);
            }
        }
        __syncthreads();
    }
    #pragma unroll
    for (int mi = 0; mi < 2; ++mi)
    #pragma unroll
    for (int ni = 0; ni < 4; ++ni)
    #pragma unroll
    for (int r = 0; r < 4; ++r) {
        int m_l = wm + mi*16 + (l>>4)*4 + r;
        int n_l = wn + ni*16 + (l&15);
        int bt = bt0 + m_l, h = h0 + n_l;
        float z = acc[mi][ni][r] + bb[h];
        belta[(size_t)bt*H_ + h] = (_Float16)__expf(-fmaxf(z, 0.f));
    }
}

// ---------------- group barrier (64 blocks, relaxed agent atomics) ----------------
__device__ __forceinline__ void group_barrier(int* flags, int gbase, int j, int it) {
    waitv0_();                 // drain inline-asm stores before publishing
    __syncthreads();
    if (threadIdx.x == 0)
        __hip_atomic_store(&flags[gbase + j], it, __ATOMIC_RELAXED, __HIP_MEMORY_SCOPE_AGENT);
    for (;;) {
        int v = __hip_atomic_load(&flags[gbase + (threadIdx.x & 63)],
                                  __ATOMIC_RELAXED, __HIP_MEMORY_SCOPE_AGENT);
        if (__syncthreads_count(v < it) == 0) break;
        __builtin_amdgcn_s_sleep(2);
    }
}

// ---------------- recurrent scan: LDS weights (k-major) + fragment-direct A ----------------
__global__ void __launch_bounds__(256, 1) recur_k(
    const _Float16* __restrict__ xh,     // (B,T,IN) fp16, plain cached
    const _Float16* __restrict__ belh,   // (B,T,H) fp16, plain cached
    const float* __restrict__ W1, const float* __restrict__ W2, const float* __restrict__ W3,
    const float* __restrict__ b1, const float* __restrict__ b2, const float* __restrict__ b3,
    const float* __restrict__ Wo,
    _Float16* __restrict__ ssh,          // (256,1024) scaled state — coherent exchange
    _Float16* __restrict__ rsh,          // (256,1024) r*state — coherent exchange
    int* flags, float* __restrict__ outacc)
{
    __shared__ __align__(16) char smem[147456];
    const int bid = blockIdx.x, tid = threadIdx.x;
    const int g = bid >> 6, j = bid & 63;
    const int gbase = g*64, grow0 = g*64;
    const int w = tid >> 6;              // wave = M-fragment index (rows w*16..w*16+15)
    const int l = tid & 63;
    const int lh = l >> 4;               // k-slot
    const int ll = l & 15;               // A-row / B-row within fragment

    // ---- prologue: weight slices -> LDS, K-MAJOR (f32->f16) ----
    for (int u = tid; u < 32*192; u += 256) {        // W12: 32 rows x 192 k8-slots
        int row = u / 192, slot = u - row*192;
        const float* src = (row < 16) ? (W1 + ((size_t)(16*j + row))*K1 + slot*8)
                                      : (W2 + ((size_t)(16*j + row-16))*K1 + slot*8);
        float4 f0 = *(const float4*)src, f1 = *(const float4*)(src+4);
        f16x8 h;
        h[0]=(_Float16)f0.x; h[1]=(_Float16)f0.y; h[2]=(_Float16)f0.z; h[3]=(_Float16)f0.w;
        h[4]=(_Float16)f1.x; h[5]=(_Float16)f1.y; h[6]=(_Float16)f1.z; h[7]=(_Float16)f1.w;
        *(f16x8*)(smem + W12_OFF + (slot*32 + row)*16) = h;
    }
    for (int u = tid; u < 16*192; u += 256) {        // W3: 16 rows x 192 k8-slots
        int row = u / 192, slot = u - row*192;
        const float* src = W3 + ((size_t)(16*j + row))*K1 + slot*8;
        float4 f0 = *(const float4*)src, f1 = *(const float4*)(src+4);
        f16x8 h;
        h[0]=(_Float16)f0.x; h[1]=(_Float16)f0.y; h[2]=(_Float16)f0.z; h[3]=(_Float16)f0.w;
        h[4]=(_Float16)f1.x; h[5]=(_Float16)f1.y; h[6]=(_Float16)f1.z; h[7]=(_Float16)f1.w;
        *(f16x8*)(smem + W3_OFF + (slot*16 + row)*16) = h;
    }
    __syncthreads();

    const int colU = (j<<4) + ll;                    // owned output column
    const float b1c = b1[colU], b2c = b2[colU], b3c = b3[colU];
    const float woc = Wo[colU];
    const int wb12 = lh*512 + ll*16;                 // per-lane LDS byte offsets
    const int wb3  = lh*256 + ll*16;

    // per-lane A-load bases: row = grow0 + w*16 + ll, k-offset lh*8
    const _Float16* srow_s = ssh + ((size_t)(grow0 + w*16 + ll) << 10) + lh*8;
    const _Float16* srow_r = rsh + ((size_t)(grow0 + w*16 + ll) << 10) + lh*8;
    const _Float16* xrow   = xh + (size_t)(grow0 + w*16 + ll) * T_ * IN_ + lh*8;
    const int crow0 = grow0 + w*16 + lh*4;           // epilogue rows (+r)

    float S_reg[4] = {0.f,0.f,0.f,0.f};
    float pout[4]  = {0.f,0.f,0.f,0.f};
    uint4 ab[8][4];                                  // depth-8 ring (128 VGPRs)
    int it = 0;

    // issue macros (4 x b128 each)
    #define ISSX(SX, DST) do { _Pragma("unroll") for (int kf=0;kf<4;++kf) \
        DST[kf] = ld_b128(xrt + (SX)*128 + kf*32); } while(0)
    #define ISSS(SC, DST) do { _Pragma("unroll") for (int kf=0;kf<4;++kf) \
        DST[kf] = ld_coh_b128(srow_s + (SC)*128 + kf*32); } while(0)
    #define ISSR(SC, DST) do { _Pragma("unroll") for (int kf=0;kf<4;++kf) \
        DST[kf] = ld_coh_b128(srow_r + (SC)*128 + kf*32); } while(0)
    // MFMA consume: S = absolute weight k-section (0..11), SL = ab slot
    #define MFMASEC1(S, SL) do { \
        _Pragma("unroll") for (int kf = 0; kf < 4; ++kf) { \
            f16x8 a = *(const f16x8*)&ab[SL][kf]; \
            f16x8 b0 = *(const f16x8*)(smem + W12_OFF + (S)*8192 + kf*2048 +   0 + wb12); \
            f16x8 b1 = *(const f16x8*)(smem + W12_OFF + (S)*8192 + kf*2048 + 256 + wb12); \
            acc1[0] = __builtin_amdgcn_mfma_f32_16x16x32_f16(a, b0, acc1[0], 0,0,0); \
            acc1[1] = __builtin_amdgcn_mfma_f32_16x16x32_f16(a, b1, acc1[1], 0,0,0); \
        } } while(0)
    #define MFMASEC2(S, SL) do { \
        _Pragma("unroll") for (int kf = 0; kf < 4; ++kf) { \
            f16x8 a = *(const f16x8*)&ab[SL][kf]; \
            f16x8 b = *(const f16x8*)(smem + W3_OFF + (S)*4096 + kf*1024 + wb3); \
            acc2 = __builtin_amdgcn_mfma_f32_16x16x32_f16(a, b, acc2, 0,0,0); \
        } } while(0)

    for (int t = 0; t < T_; ++t) {
        const _Float16* xrt = xrow + (size_t)t * IN_;
        float u_reg[4];
        { // ---- P1: [u|r] = sigmoid([state|x_t] @ W12^T + b) ----
            ISSX(0, ab[0]); ISSX(1, ab[1]); ISSX(2, ab[2]); ISSX(3, ab[3]);
            ISSS(0, ab[4]); ISSS(1, ab[5]); ISSS(2, ab[6]); ISSS(3, ab[7]);
            f32x4 acc1[2] = {};
            WAITV(28); MFMASEC1(8, 0);  ISSS(4, ab[0]);
            WAITV(28); MFMASEC1(9, 1);  ISSS(5, ab[1]);
            WAITV(28); MFMASEC1(10,2);  ISSS(6, ab[2]);
            WAITV(28); MFMASEC1(11,3);  ISSS(7, ab[3]);
            WAITV(28); MFMASEC1(0, 4);
            WAITV(24); MFMASEC1(1, 5);
            WAITV(20); MFMASEC1(2, 6);
            WAITV(16); MFMASEC1(3, 7);
            WAITV(12); MFMASEC1(4, 0);
            WAITV(8);  MFMASEC1(5, 1);
            WAITV(4);  MFMASEC1(6, 2);
            WAITV(0);  MFMASEC1(7, 3);
            #pragma unroll
            for (int r = 0; r < 4; ++r) {
                u_reg[r] = sigmoidf_(acc1[0][r] + b1c);
                float rr = sigmoidf_(acc1[1][r] + b2c);
                _Float16 hv = (_Float16)(rr * S_reg[r]);
                st_coh_u16(rsh + ((size_t)(crow0 + r) << 10) + colU,
                           (unsigned)*(unsigned short*)&hv);
            }
        }
        group_barrier(flags, gbase, j, ++it);
        { // ---- P2: ns = tanh([r*s|x_t] @ W3^T + b3); state update ----
            const int tn = (t < T_-1) ? t+1 : t;     // belta prefetch (clamped)
            unsigned bv[4];
            ISSX(0, ab[0]); ISSX(1, ab[1]); ISSX(2, ab[2]); ISSX(3, ab[3]);
            ISSR(0, ab[4]); ISSR(1, ab[5]); ISSR(2, ab[6]); ISSR(3, ab[7]);
            f32x4 acc2 = {};
            WAITV(28); MFMASEC2(8, 0);  ISSR(4, ab[0]);
            WAITV(28); MFMASEC2(9, 1);  ISSR(5, ab[1]);
            WAITV(28); MFMASEC2(10,2);  ISSR(6, ab[2]);
            WAITV(28); MFMASEC2(11,3);  ISSR(7, ab[3]);
            #pragma unroll
            for (int r = 0; r < 4; ++r)
                bv[r] = ld_u16(belh + ((size_t)(crow0 + r)*T_ + tn)*H_ + colU);
            WAITV(32); MFMASEC2(0, 4);
            WAITV(28); MFMASEC2(1, 5);
            WAITV(24); MFMASEC2(2, 6);
            WAITV(20); MFMASEC2(3, 7);
            WAITV(16); MFMASEC2(4, 0);
            WAITV(12); MFMASEC2(5, 1);
            WAITV(8);  MFMASEC2(6, 2);
            WAITV(4);  MFMASEC2(7, 3);
            WAITV(0);                                 // belta ready
            #pragma unroll
            for (int r = 0; r < 4; ++r) {
                float ns = tanhf_(acc2[r] + b3c);
                float sn = (1.f - u_reg[r])*S_reg[r] + u_reg[r]*ns;
                if (t < T_-1) {
                    unsigned short us = (unsigned short)bv[r];
                    float bel = (float)(*(_Float16*)&us);
                    float ss = bel * sn;
                    S_reg[r] = ss;
                    _Float16 hs = (_Float16)ss;
                    st_coh_u16(ssh + ((size_t)(crow0 + r) << 10) + colU,
                               (unsigned)*(unsigned short*)&hs);
                } else {
                    pout[r] = sn * woc;
                }
            }
        }
        group_barrier(flags, gbase, j, ++it);
    }
    #undef MFMASEC1
    #undef MFMASEC2
    #undef ISSX
    #undef ISSS
    #undef ISSR
    // ---- final: sum pout over the block's 16 cols (ll), atomicAdd per row ----
    #pragma unroll
    for (int r = 0; r < 4; ++r) {
        float v = pout[r];
        v += __shfl_xor(v, 1, 64);
        v += __shfl_xor(v, 2, 64);
        v += __shfl_xor(v, 4, 64);
        v += __shfl_xor(v, 8, 64);
        if (ll == 0) atomicAdd(&outacc[crow0 + r], v);
    }
}

__global__ void finish_k(const float* __restrict__ acc, const float* __restrict__ bo,
                         float* __restrict__ out) {
    int i = threadIdx.x;
    out[i] = sigmoidf_(acc[i] + bo[0]);
}

extern "C" void kernel_launch(void* const* d_in, const int* in_sizes, int n_in,
                              void* d_out, int out_size, void* d_ws, size_t ws_size,
                              hipStream_t stream) {
    const float* x   = (const float*)d_in[0];
    const float* td  = (const float*)d_in[1];
    const float* Wb  = (const float*)d_in[2];
    const float* bb  = (const float*)d_in[3];
    const float* W1  = (const float*)d_in[4];
    const float* b1  = (const float*)d_in[5];
    const float* W2  = (const float*)d_in[6];
    const float* b2  = (const float*)d_in[7];
    const float* W3  = (const float*)d_in[8];
    const float* b3  = (const float*)d_in[9];
    const float* Wo  = (const float*)d_in[10];
    const float* bo  = (const float*)d_in[11];
    float* out = (float*)d_out;

    char* p = (char*)d_ws;
    auto carve = [&](size_t bytes) { char* r = p; p += (bytes + 255) & ~(size_t)255; return r; };
    int*      bar    = (int*)      carve(1024);            // 256 flags
    float*    outacc = (float*)    carve(1024);            // 256 partial sums
    _Float16* ssh    = (_Float16*) carve((size_t)B_*H_*2); // scaled state exchange
    _Float16* rsh    = (_Float16*) carve((size_t)B_*H_*2); // r*state exchange
    _Float16* xh     = (_Float16*) carve((size_t)NT*IN_*2);
    _Float16* tdh    = (_Float16*) carve((size_t)NT*IN_*2);
    _Float16* belh   = (_Float16*) carve((size_t)NT*H_*2);
    _Float16* Wbh    = (_Float16*) carve((size_t)H_*IN_*2);

    // zero: flags + outacc + ssh (contiguous at front of d_ws)
    size_t zbytes = 1024 + 1024 + (size_t)B_*H_*2;
    (void)hipMemsetAsync(bar, 0, zbytes, stream);

    const int thr = 256;
    int n8;
    n8 = NT*IN_/8;    cvt_f32_f16_k<<<(n8+thr-1)/thr, thr, 0, stream>>>(x,  xh,  n8);
    n8 = NT*IN_/8;    cvt_f32_f16_k<<<(n8+thr-1)/thr, thr, 0, stream>>>(td, tdh, n8);
    n8 = H_*IN_/8;    cvt_f32_f16_k<<<(n8+thr-1)/thr, thr, 0, stream>>>(Wb, Wbh, n8);

    belta_gemm_k<<<(NT/64)*(H_/128), 256, 0, stream>>>(tdh, Wbh, bb, belh);

    recur_k<<<256, 256, 0, stream>>>(xh, belh, W1, W2, W3, b1, b2, b3, Wo,
                                     ssh, rsh, bar, outacc);
    finish_k<<<1, 256, 0, stream>>>(outacc, bo, out);
}

// Round 11
// 2059.394 us; speedup vs baseline: 1.7974x; 1.0784x over previous
//
#include <hip/hip_runtime.h>
#include <hip/hip_fp16.h>

#define B_  256
#define T_  96
#define IN_ 512
#define H_  1024
#define K1  1536          // H + IN
#define NT  (B_*T_)       // 24576

// recur_k: 4 groups x 64 blocks; group owns 64 batch rows; block owns 16 cols
// of W1/W2/W3. Persistent LDS weights, K-MAJOR layout (conflict-free b128):
//   W12: addr = W12_OFF + (k8*32 + row)*16, k8 = k/8 in [0,192), row in [0,32)
//   W3 : addr = W3_OFF  + (k8*16 + row)*16, row in [0,16)
#define W12_OFF 0          // 98304 B
#define W3_OFF  98304      // 49152 B -> total 147456 B
typedef _Float16 f16x8 __attribute__((ext_vector_type(8)));
typedef float    f32x4 __attribute__((ext_vector_type(4)));
typedef float    f32x2 __attribute__((ext_vector_type(2)));

__device__ __forceinline__ float sigmoidf_(float z) { return 1.f/(1.f+__expf(-z)); }
__device__ __forceinline__ float tanhf_(float z)    { return 1.f - 2.f/(__expf(2.f*z)+1.f); }

// coherent (cross-XCD) access: bypass L1 + per-XCD L2
__device__ __forceinline__ uint2 ld_coh_b64(const void* p){
    uint2 r; asm volatile("global_load_dwordx2 %0, %1, off sc0 sc1" : "=&v"(r) : "v"(p)); return r;
}
__device__ __forceinline__ uint4 ld_b128(const void* p){
    uint4 r; asm volatile("global_load_dwordx4 %0, %1, off" : "=&v"(r) : "v"(p)); return r;
}
__device__ __forceinline__ unsigned ld_u16(const void* p){
    unsigned r; asm volatile("global_load_ushort %0, %1, off" : "=&v"(r) : "v"(p)); return r;
}
__device__ __forceinline__ void st_coh_u8(void* p, unsigned v){
    asm volatile("global_store_byte %0, %1, off sc0 sc1" :: "v"(p), "v"(v) : "memory");
}
#define WAITV(n) do { asm volatile("s_waitcnt vmcnt(" #n ")" ::: "memory"); \
                      __builtin_amdgcn_sched_barrier(0); } while(0)
__device__ __forceinline__ void waitv0_(){ asm volatile("s_waitcnt vmcnt(0)" ::: "memory"); }

// fp8 e4m3 helpers (OCP on gfx950)
__device__ __forceinline__ unsigned to_fp8(float x){
    return (unsigned)__builtin_amdgcn_cvt_pk_fp8_f32(x, x, 0, false) & 0xFFu;
}
__device__ __forceinline__ f16x8 expand_fp8(uint2 v){
    f32x2 p0 = __builtin_amdgcn_cvt_pk_f32_fp8(v.x, false);
    f32x2 p1 = __builtin_amdgcn_cvt_pk_f32_fp8(v.x, true);
    f32x2 p2 = __builtin_amdgcn_cvt_pk_f32_fp8(v.y, false);
    f32x2 p3 = __builtin_amdgcn_cvt_pk_f32_fp8(v.y, true);
    f16x8 o;
    o[0]=(_Float16)p0[0]; o[1]=(_Float16)p0[1];
    o[2]=(_Float16)p1[0]; o[3]=(_Float16)p1[1];
    o[4]=(_Float16)p2[0]; o[5]=(_Float16)p2[1];
    o[6]=(_Float16)p3[0]; o[7]=(_Float16)p3[1];
    return o;
}

// ---------------- prep: fp32 -> fp16 ----------------
__global__ void cvt_f32_f16_k(const float* __restrict__ src, _Float16* __restrict__ dst, int n8) {
    int i = blockIdx.x*blockDim.x + threadIdx.x;
    if (i >= n8) return;
    const float4* s = (const float4*)src;
    float4 a = s[2*(size_t)i], b = s[2*(size_t)i+1];
    f16x8 o;
    o[0]=(_Float16)a.x; o[1]=(_Float16)a.y; o[2]=(_Float16)a.z; o[3]=(_Float16)a.w;
    o[4]=(_Float16)b.x; o[5]=(_Float16)b.y; o[6]=(_Float16)b.z; o[7]=(_Float16)b.w;
    *(f16x8*)(dst + 8*(size_t)i) = o;
}

// ---------------- belta = exp(-relu(td @ Wb^T + bb)) ----------------
__global__ void __launch_bounds__(256) belta_gemm_k(const _Float16* __restrict__ td,
                                                    const _Float16* __restrict__ Wbh,
                                                    const float* __restrict__ bb,
                                                    _Float16* __restrict__ belta) {
    __shared__ _Float16 As[64][136];
    __shared__ _Float16 Bs[128][136];
    const int bid = blockIdx.x;
    const int mt = bid >> 3, nt = bid & 7;
    const int bt0 = mt*64, h0 = nt*128;
    const int tid = threadIdx.x;
    const int w = tid >> 6, l = tid & 63;
    const int wm = (w>>1)*32, wn = (w&1)*64;
    f32x4 acc[2][4] = {};
    for (int kc = 0; kc < 4; ++kc) {
        const int kbase = kc*128;
        #pragma unroll
        for (int p = 0; p < 4; ++p) {
            int unit = tid + 256*p; int r = unit>>4, cu = unit&15;
            *(uint4*)&As[r][cu*8] = *(const uint4*)(td + (size_t)(bt0+r)*IN_ + kbase + cu*8);
        }
        #pragma unroll
        for (int p = 0; p < 8; ++p) {
            int unit = tid + 256*p; int r = unit>>4, cu = unit&15;
            *(uint4*)&Bs[r][cu*8] = *(const uint4*)(Wbh + (size_t)(h0+r)*IN_ + kbase + cu*8);
        }
        __syncthreads();
        #pragma unroll
        for (int ks = 0; ks < 4; ++ks) {
            const int kk = ks*32 + (l>>4)*8;
            f16x8 a0 = *(const f16x8*)&As[wm +      (l&15)][kk];
            f16x8 a1 = *(const f16x8*)&As[wm + 16 + (l&15)][kk];
            #pragma unroll
            for (int ni = 0; ni < 4; ++ni) {
                f16x8 b = *(const f16x8*)&Bs[wn + ni*16 + (l&15)][kk];
                acc[0][ni] = __builtin_amdgcn_mfma_f32_16x16x32_f16(a0, b, acc[0][ni], 0,0,0);
                acc[1][ni] = __builtin_amdgcn_mfma_f32_16x16x32_f16(a1, b, acc[1][ni], 0,0,0);
            }
        }
        __syncthreads();
    }
    #pragma unroll
    for (int mi = 0; mi < 2; ++mi)
    #pragma unroll
    for (int ni = 0; ni < 4; ++ni)
    #pragma unroll
    for (int r = 0; r < 4; ++r) {
        int m_l = wm + mi*16 + (l>>4)*4 + r;
        int n_l = wn + ni*16 + (l&15);
        int bt = bt0 + m_l, h = h0 + n_l;
        float z = acc[mi][ni][r] + bb[h];
        belta[(size_t)bt*H_ + h] = (_Float16)__expf(-fmaxf(z, 0.f));
    }
}

// ---------------- group barrier (64 blocks, relaxed agent atomics) ----------------
__device__ __forceinline__ void group_barrier(int* flags, int gbase, int j, int it) {
    waitv0_();                 // drain inline-asm stores before publishing
    __syncthreads();
    if (threadIdx.x == 0)
        __hip_atomic_store(&flags[gbase + j], it, __ATOMIC_RELAXED, __HIP_MEMORY_SCOPE_AGENT);
    for (;;) {
        int v = __hip_atomic_load(&flags[gbase + (threadIdx.x & 63)],
                                  __ATOMIC_RELAXED, __HIP_MEMORY_SCOPE_AGENT);
        if (__syncthreads_count(v < it) == 0) break;
        __builtin_amdgcn_s_sleep(2);
    }
}

// ---------------- recurrent scan: LDS f16 weights + fp8 coherent exchange ----------------
__global__ void __launch_bounds__(256, 1) recur_k(
    const _Float16* __restrict__ xh,     // (B,T,IN) fp16, plain cached
    const _Float16* __restrict__ belh,   // (B,T,H) fp16, plain cached
    const float* __restrict__ W1, const float* __restrict__ W2, const float* __restrict__ W3,
    const float* __restrict__ b1, const float* __restrict__ b2, const float* __restrict__ b3,
    const float* __restrict__ Wo,
    unsigned char* __restrict__ ssh,     // (256,1024) fp8 scaled state — coherent exchange
    unsigned char* __restrict__ rsh,     // (256,1024) fp8 r*state — coherent exchange
    int* flags, float* __restrict__ outacc)
{
    __shared__ __align__(16) char smem[147456];
    const int bid = blockIdx.x, tid = threadIdx.x;
    const int g = bid >> 6, j = bid & 63;
    const int gbase = g*64, grow0 = g*64;
    const int w = tid >> 6;              // wave = M-fragment index (rows w*16..w*16+15)
    const int l = tid & 63;
    const int lh = l >> 4;               // k-slot
    const int ll = l & 15;               // A-row / B-row within fragment

    // ---- prologue: weight slices -> LDS, K-MAJOR f16 (f32->f16) ----
    for (int u = tid; u < 32*192; u += 256) {        // W12: 32 rows x 192 k8-slots
        int row = u / 192, slot = u - row*192;
        const float* src = (row < 16) ? (W1 + ((size_t)(16*j + row))*K1 + slot*8)
                                      : (W2 + ((size_t)(16*j + row-16))*K1 + slot*8);
        float4 f0 = *(const float4*)src, f1 = *(const float4*)(src+4);
        f16x8 h;
        h[0]=(_Float16)f0.x; h[1]=(_Float16)f0.y; h[2]=(_Float16)f0.z; h[3]=(_Float16)f0.w;
        h[4]=(_Float16)f1.x; h[5]=(_Float16)f1.y; h[6]=(_Float16)f1.z; h[7]=(_Float16)f1.w;
        *(f16x8*)(smem + W12_OFF + (slot*32 + row)*16) = h;
    }
    for (int u = tid; u < 16*192; u += 256) {        // W3: 16 rows x 192 k8-slots
        int row = u / 192, slot = u - row*192;
        const float* src = W3 + ((size_t)(16*j + row))*K1 + slot*8;
        float4 f0 = *(const float4*)src, f1 = *(const float4*)(src+4);
        f16x8 h;
        h[0]=(_Float16)f0.x; h[1]=(_Float16)f0.y; h[2]=(_Float16)f0.z; h[3]=(_Float16)f0.w;
        h[4]=(_Float16)f1.x; h[5]=(_Float16)f1.y; h[6]=(_Float16)f1.z; h[7]=(_Float16)f1.w;
        *(f16x8*)(smem + W3_OFF + (slot*16 + row)*16) = h;
    }
    __syncthreads();

    const int colU = (j<<4) + ll;                    // owned output column
    const float b1c = b1[colU], b2c = b2[colU], b3c = b3[colU];
    const float woc = Wo[colU];
    const int wb12 = lh*512 + ll*16;                 // per-lane LDS byte offsets
    const int wb3  = lh*256 + ll*16;

    // per-lane A-load bases: row = grow0 + w*16 + ll, k-offset lh*8
    const unsigned char* srow_s = ssh + ((size_t)(grow0 + w*16 + ll) << 10) + lh*8;
    const unsigned char* srow_r = rsh + ((size_t)(grow0 + w*16 + ll) << 10) + lh*8;
    const _Float16* xrow = xh + (size_t)(grow0 + w*16 + ll) * T_ * IN_ + lh*8;
    const int crow0 = grow0 + w*16 + lh*4;           // epilogue rows (+r)

    float S_reg[4] = {0.f,0.f,0.f,0.f};
    float pout[4]  = {0.f,0.f,0.f,0.f};
    uint4 abx[4][4];                                 // x frags (f16), 64 VGPR
    uint2 abs_[8][4];                                // coherent fp8 frags, 64 VGPR
    int it = 0;

    // issue macros
    #define ISSX(SX) do { _Pragma("unroll") for (int kf=0;kf<4;++kf) \
        abx[SX][kf] = ld_b128(xrt + (SX)*128 + kf*32); } while(0)
    #define ISSS(SC) do { _Pragma("unroll") for (int kf=0;kf<4;++kf) \
        abs_[SC][kf] = ld_coh_b64(srow_s + (SC)*128 + kf*32); } while(0)
    #define ISSR(SC) do { _Pragma("unroll") for (int kf=0;kf<4;++kf) \
        abs_[SC][kf] = ld_coh_b64(srow_r + (SC)*128 + kf*32); } while(0)
    // consume: S = absolute weight k-section (0..11)
    #define MF1X(S, SX) do { \
        _Pragma("unroll") for (int kf = 0; kf < 4; ++kf) { \
            f16x8 a = *(const f16x8*)&abx[SX][kf]; \
            f16x8 b0 = *(const f16x8*)(smem + W12_OFF + (S)*8192 + kf*2048 +   0 + wb12); \
            f16x8 b1 = *(const f16x8*)(smem + W12_OFF + (S)*8192 + kf*2048 + 256 + wb12); \
            acc1[0] = __builtin_amdgcn_mfma_f32_16x16x32_f16(a, b0, acc1[0], 0,0,0); \
            acc1[1] = __builtin_amdgcn_mfma_f32_16x16x32_f16(a, b1, acc1[1], 0,0,0); \
        } } while(0)
    #define MF1S(S, SC) do { \
        _Pragma("unroll") for (int kf = 0; kf < 4; ++kf) { \
            f16x8 a = expand_fp8(abs_[SC][kf]); \
            f16x8 b0 = *(const f16x8*)(smem + W12_OFF + (S)*8192 + kf*2048 +   0 + wb12); \
            f16x8 b1 = *(const f16x8*)(smem + W12_OFF + (S)*8192 + kf*2048 + 256 + wb12); \
            acc1[0] = __builtin_amdgcn_mfma_f32_16x16x32_f16(a, b0, acc1[0], 0,0,0); \
            acc1[1] = __builtin_amdgcn_mfma_f32_16x16x32_f16(a, b1, acc1[1], 0,0,0); \
        } } while(0)
    #define MF2X(S, SX) do { \
        _Pragma("unroll") for (int kf = 0; kf < 4; ++kf) { \
            f16x8 a = *(const f16x8*)&abx[SX][kf]; \
            f16x8 b = *(const f16x8*)(smem + W3_OFF + (S)*4096 + kf*1024 + wb3); \
            acc2 = __builtin_amdgcn_mfma_f32_16x16x32_f16(a, b, acc2, 0,0,0); \
        } } while(0)
    #define MF2S(S, SC) do { \
        _Pragma("unroll") for (int kf = 0; kf < 4; ++kf) { \
            f16x8 a = expand_fp8(abs_[SC][kf]); \
            f16x8 b = *(const f16x8*)(smem + W3_OFF + (S)*4096 + kf*1024 + wb3); \
            acc2 = __builtin_amdgcn_mfma_f32_16x16x32_f16(a, b, acc2, 0,0,0); \
        } } while(0)

    for (int t = 0; t < T_; ++t) {
        const _Float16* xrt = xrow + (size_t)t * IN_;
        float u_reg[4];
        { // ---- P1: [u|r] = sigmoid([state|x_t] @ W12^T + b) ----
            ISSX(0); ISSX(1); ISSX(2); ISSX(3);
            ISSS(0); ISSS(1); ISSS(2); ISSS(3);
            f32x4 acc1[2] = {};
            WAITV(28); MF1X(8, 0);  ISSS(4);
            WAITV(28); MF1X(9, 1);  ISSS(5);
            WAITV(28); MF1X(10,2);  ISSS(6);
            WAITV(28); MF1X(11,3);  ISSS(7);
            WAITV(28); MF1S(0, 0);
            WAITV(24); MF1S(1, 1);
            WAITV(20); MF1S(2, 2);
            WAITV(16); MF1S(3, 3);
            WAITV(12); MF1S(4, 4);
            WAITV(8);  MF1S(5, 5);
            WAITV(4);  MF1S(6, 6);
            WAITV(0);  MF1S(7, 7);
            #pragma unroll
            for (int r = 0; r < 4; ++r) {
                u_reg[r] = sigmoidf_(acc1[0][r] + b1c);
                float rr = sigmoidf_(acc1[1][r] + b2c);
                st_coh_u8(rsh + ((size_t)(crow0 + r) << 10) + colU, to_fp8(rr * S_reg[r]));
            }
        }
        group_barrier(flags, gbase, j, ++it);
        { // ---- P2: ns = tanh([r*s|x_t] @ W3^T + b3); state update ----
            const int tn = (t < T_-1) ? t+1 : t;     // belta prefetch (clamped)
            unsigned bv[4];
            ISSX(0); ISSX(1); ISSX(2); ISSX(3);
            ISSR(0); ISSR(1); ISSR(2); ISSR(3);
            f32x4 acc2 = {};
            WAITV(28); MF2X(8, 0);  ISSR(4);
            WAITV(28); MF2X(9, 1);  ISSR(5);
            WAITV(28); MF2X(10,2);  ISSR(6);
            WAITV(28); MF2X(11,3);  ISSR(7);
            #pragma unroll
            for (int r = 0; r < 4; ++r)
                bv[r] = ld_u16(belh + ((size_t)(crow0 + r)*T_ + tn)*H_ + colU);
            WAITV(32); MF2S(0, 0);
            WAITV(28); MF2S(1, 1);
            WAITV(24); MF2S(2, 2);
            WAITV(20); MF2S(3, 3);
            WAITV(16); MF2S(4, 4);
            WAITV(12); MF2S(5, 5);
            WAITV(8);  MF2S(6, 6);
            WAITV(4);  MF2S(7, 7);
            WAITV(0);                                 // belta ready
            #pragma unroll
            for (int r = 0; r < 4; ++r) {
                float ns = tanhf_(acc2[r] + b3c);
                float sn = (1.f - u_reg[r])*S_reg[r] + u_reg[r]*ns;
                if (t < T_-1) {
                    unsigned short us = (unsigned short)bv[r];
                    float bel = (float)(*(_Float16*)&us);
                    float ss = bel * sn;
                    S_reg[r] = ss;
                    st_coh_u8(ssh + ((size_t)(crow0 + r) << 10) + colU, to_fp8(ss));
                } else {
                    pout[r] = sn * woc;
                }
            }
        }
        group_barrier(flags, gbase, j, ++it);
    }
    #undef MF1X
    #undef MF1S
    #undef MF2X
    #undef MF2S
    #undef ISSX
    #undef ISSS
    #undef ISSR
    // ---- final: sum pout over the block's 16 cols (ll), atomicAdd per row ----
    #pragma unroll
    for (int r = 0; r < 4; ++r) {
        float v = pout[r];
        v += __shfl_xor(v, 1, 64);
        v += __shfl_xor(v, 2, 64);
        v += __shfl_xor(v, 4, 64);
        v += __shfl_xor(v, 8, 64);
        if (ll == 0) atomicAdd(&outacc[crow0 + r], v);
    }
}

__global__ void finish_k(const float* __restrict__ acc, const float* __restrict__ bo,
                         float* __restrict__ out) {
    int i = threadIdx.x;
    out[i] = sigmoidf_(acc[i] + bo[0]);
}

extern "C" void kernel_launch(void* const* d_in, const int* in_sizes, int n_in,
                              void* d_out, int out_size, void* d_ws, size_t ws_size,
                              hipStream_t stream) {
    const float* x   = (const float*)d_in[0];
    const float* td  = (const float*)d_in[1];
    const float* Wb  = (const float*)d_in[2];
    const float* bb  = (const float*)d_in[3];
    const float* W1  = (const float*)d_in[4];
    const float* b1  = (const float*)d_in[5];
    const float* W2  = (const float*)d_in[6];
    const float* b2  = (const float*)d_in[7];
    const float* W3  = (const float*)d_in[8];
    const float* b3  = (const float*)d_in[9];
    const float* Wo  = (const float*)d_in[10];
    const float* bo  = (const float*)d_in[11];
    float* out = (float*)d_out;

    char* p = (char*)d_ws;
    auto carve = [&](size_t bytes) { char* r = p; p += (bytes + 255) & ~(size_t)255; return r; };
    int*           bar    = (int*)           carve(1024);            // 256 flags
    float*         outacc = (float*)         carve(1024);            // 256 partial sums
    unsigned char* ssh    = (unsigned char*) carve((size_t)B_*H_);   // fp8 state exchange
    unsigned char* rsh    = (unsigned char*) carve((size_t)B_*H_);   // fp8 r*state exchange
    _Float16*      xh     = (_Float16*)      carve((size_t)NT*IN_*2);
    _Float16*      tdh    = (_Float16*)      carve((size_t)NT*IN_*2);
    _Float16*      belh   = (_Float16*)      carve((size_t)NT*H_*2);
    _Float16*      Wbh    = (_Float16*)      carve((size_t)H_*IN_*2);

    // zero: flags + outacc + ssh (contiguous at front of d_ws)
    size_t zbytes = 1024 + 1024 + (size_t)B_*H_;
    (void)hipMemsetAsync(bar, 0, zbytes, stream);

    const int thr = 256;
    int n8;
    n8 = NT*IN_/8;    cvt_f32_f16_k<<<(n8+thr-1)/thr, thr, 0, stream>>>(x,  xh,  n8);
    n8 = NT*IN_/8;    cvt_f32_f16_k<<<(n8+thr-1)/thr, thr, 0, stream>>>(td, tdh, n8);
    n8 = H_*IN_/8;    cvt_f32_f16_k<<<(n8+thr-1)/thr, thr, 0, stream>>>(Wb, Wbh, n8);

    belta_gemm_k<<<(NT/64)*(H_/128), 256, 0, stream>>>(tdh, Wbh, bb, belh);

    recur_k<<<256, 256, 0, stream>>>(xh, belh, W1, W2, W3, b1, b2, b3, Wo,
                                     ssh, rsh, bar, outacc);
    finish_k<<<1, 256, 0, stream>>>(outacc, bo, out);
}